// Round 1
// 647.808 us; speedup vs baseline: 1.0707x; 1.0707x over previous
//
#include <hip/hip_runtime.h>

#define Bn 16
#define Cn 20
#define Hn 512
#define Wn 512
#define HWn (Hn*Wn)
#define Rn 16      // rows per thread in final_kernel (fetch ratio (Rn+4)/Rn = 1.25)
#define CGn 4      // channel groups (occupancy: 4x threads vs all-20-channels-per-thread)
#define CPG 5      // channels per group

typedef float f32x4 __attribute__((ext_vector_type(4)));

// Mask planes, fully rewritten every kernel_launch call.
__device__ unsigned char g_a1[(size_t)Bn*HWn];
__device__ unsigned char g_a2[(size_t)Bn*HWn];

// Step-1 mask (fall_left=True, shift_w=+1):
// a1[h,w] = (ch0[h,w]==3) & (d[h,w-1]-d[h,w] >= 0) & (d[h-1,w]-d[h,w] < 0) & (d[h-1,w-1]-d[h,w] < 0)
__global__ __launch_bounds__(256) void mask1_kernel(const float* __restrict__ world) {
    int idx = blockIdx.x * 256 + threadIdx.x;           // over Bn*Hn*Wn (2^22)
    int w = idx & (Wn - 1);
    int h = (idx >> 9) & (Hn - 1);
    int b = idx >> 18;
    const float* e = world + (size_t)b * Cn * HWn;      // channel 0
    const float* d = e + HWn;                           // channel 1
    int wm = (w - 1) & (Wn - 1);
    int hm = (h - 1) & (Hn - 1);
    float dc  = d[h  * Wn + w];
    float df  = d[h  * Wn + wm];
    float da  = d[hm * Wn + w];
    float dfa = d[hm * Wn + wm];
    bool a = (e[h * Wn + w] == 3.0f) & (df - dc >= 0.0f) & (da - dc < 0.0f) & (dfa - dc < 0.0f);
    g_a1[idx] = (unsigned char)a;
}

// Intermediate (post-step-1) value of plane p at (r, wc), exact reference semantics.
__device__ __forceinline__ float stepval(const float* __restrict__ p,
                                         const unsigned char* __restrict__ a1p,
                                         int r, int wc) {
    int rm = (r - 1) & (Hn - 1), rp = (r + 1) & (Hn - 1);
    unsigned char a  = a1p[r  * Wn + wc];
    unsigned char bb = a1p[rp * Wn + wc];
    float v;
    if (a)       { v = p[rm * Wn + wc]; if (bb) v += p[rp * Wn + wc]; }
    else if (bb) { v = p[rp * Wn + wc]; }
    else         { v = p[r  * Wn + wc]; }
    return v;
}

// Step-2 mask (fall_left=False, shift_w=-1), computed from on-the-fly intermediates.
__global__ __launch_bounds__(256) void mask2_kernel(const float* __restrict__ world) {
    int idx = blockIdx.x * 256 + threadIdx.x;
    int w = idx & (Wn - 1);
    int h = (idx >> 9) & (Hn - 1);
    int b = idx >> 18;
    const float* e = world + (size_t)b * Cn * HWn;
    const float* d = e + HWn;
    const unsigned char* a1p = g_a1 + (size_t)b * HWn;
    int wp = (w + 1) & (Wn - 1);
    int hm = (h - 1) & (Hn - 1);
    float I0   = stepval(e, a1p, h,  w);
    float I1c  = stepval(d, a1p, h,  w);
    float I1f  = stepval(d, a1p, h,  wp);
    float I1a  = stepval(d, a1p, hm, w);
    float I1fa = stepval(d, a1p, hm, wp);
    bool a = (I0 == 3.0f) & (I1f - I1c >= 0.0f) & (I1a - I1c < 0.0f) & (I1fa - I1c < 0.0f);
    g_a2[idx] = (unsigned char)a;
}

// Final pass: h-tiled rolling-window stencil.
// Thread = (b, channel-group of 5, h-tile of 16 rows, 4-wide w chunk).
// Coefficients are integer-valued (cm2,cm1,cp1,cp2 in {0,1}, c0 in {0,1,2});
// packed 6 bits/pixel into one u32 per row (SWAR over 4 pixels), decoded with
// bfe+cvt+fma in the inner loop. 16 coef words = 16 VGPRs, reused by all 5 channels.
__global__ __launch_bounds__(256) void final_kernel(const float* __restrict__ world,
                                                    float* __restrict__ out) {
    int t    = blockIdx.x * 256 + threadIdx.x;   // 262144 threads total
    int wq   = t & 127;                          // float4 column
    int cg   = (t >> 7) & 3;                     // channel group
    int tile = (t >> 9) & 31;                    // h tile
    int b    = t >> 14;
    int w    = wq * 4;
    int h0   = tile * Rn;

    const unsigned char* a1p = g_a1 + (size_t)b * HWn;
    const unsigned char* a2p = g_a2 + (size_t)b * HWn;

    // Mask rows needed: a1 rows h0-1 .. h0+Rn+1 (Rn+3), a2 rows h0 .. h0+Rn (Rn+1).
    unsigned int a1r[Rn + 3];
    unsigned int a2r[Rn + 1];
#pragma unroll
    for (int r = 0; r < Rn + 3; r++) {
        int h = (h0 - 1 + r) & (Hn - 1);
        a1r[r] = *(const unsigned int*)(a1p + (size_t)h * Wn + w);
    }
#pragma unroll
    for (int r = 0; r < Rn + 1; r++) {
        int h = (h0 + r) & (Hn - 1);
        a2r[r] = *(const unsigned int*)(a2p + (size_t)h * Wn + w);
    }

    // SWAR coef-bit packing: bytes of each u32 are {0,1} flags for 4 pixels.
    // bit0=cm2, bit1=cm1, bits2-3=c0 (0..2), bit4=cp1, bit5=cp2.
    const unsigned int ONE = 0x01010101u;
    unsigned int cw[Rn];
#pragma unroll
    for (int r = 0; r < Rn; r++) {
        unsigned int rm1 = a1r[r], r0 = a1r[r + 1], rp1 = a1r[r + 2], rp2 = a1r[r + 3];
        unsigned int s0 = a2r[r], s1 = a2r[r + 1];
        unsigned int z   = (s0 | s1) ^ ONE;                      // (1-s0)(1-s1)
        unsigned int cm2 = s0 & rm1;
        unsigned int cm1 = (s0 & (rm1 ^ ONE) & (r0 ^ ONE)) | (z & r0);
        unsigned int c0  = (s0 & r0) + (z & (r0 ^ ONE) & (rp1 ^ ONE)) + (s1 & rp1); // byte sum <= 2
        unsigned int cp1 = (z & rp1) | (s1 & (rp1 ^ ONE) & (rp2 ^ ONE));
        unsigned int cp2 = s1 & rp2;
        cw[r] = cm2 | (cm1 << 1) | ((c0 & ONE) << 2) | (((c0 >> 1) & ONE) << 3)
                    | (cp1 << 4) | (cp2 << 5);
    }

    const float* base  = world + ((size_t)b * Cn + (size_t)cg * CPG) * HWn + w;
    float*       obase = out   + ((size_t)b * Cn + (size_t)cg * CPG) * HWn + w;

#pragma unroll 1
    for (int c = 0; c < CPG; c++) {
        const float* p = base  + (size_t)c * HWn;
        float*       q = obase + (size_t)c * HWn;
        // rolling 5-row window; each world row loaded exactly once per thread
        f32x4 xm2 = *(const f32x4*)(p + (size_t)((h0 - 2) & (Hn - 1)) * Wn);
        f32x4 xm1 = *(const f32x4*)(p + (size_t)((h0 - 1) & (Hn - 1)) * Wn);
        f32x4 x0  = *(const f32x4*)(p + (size_t)h0 * Wn);
        f32x4 xp1 = *(const f32x4*)(p + (size_t)(h0 + 1) * Wn);
#pragma unroll
        for (int r = 0; r < Rn; r++) {
            f32x4 xp2 = *(const f32x4*)(p + (size_t)((h0 + r + 2) & (Hn - 1)) * Wn);
            unsigned int cwr = cw[r];
            f32x4 o;
#pragma unroll
            for (int j = 0; j < 4; j++) {
                unsigned int u = (cwr >> (8 * j)) & 0xffu;
                float fm2 = (float)(u & 1u);
                float fm1 = (float)((u >> 1) & 1u);
                float f0  = (float)((u >> 2) & 3u);
                float fp1 = (float)((u >> 4) & 1u);
                float fp2 = (float)((u >> 5) & 1u);
                o[j] = fm2 * xm2[j] + fm1 * xm1[j] + f0 * x0[j] + fp1 * xp1[j] + fp2 * xp2[j];
            }
            // streaming output: don't let writes evict stencil halos from L2
            __builtin_nontemporal_store(o, (f32x4*)(q + (size_t)(h0 + r) * Wn));
            xm2 = xm1; xm1 = x0; x0 = xp1; xp1 = xp2;
        }
    }
}

extern "C" void kernel_launch(void* const* d_in, const int* in_sizes, int n_in,
                              void* d_out, int out_size, void* d_ws, size_t ws_size,
                              hipStream_t stream) {
    const float* world = (const float*)d_in[0];   // (16,20,512,512) fp32; rand_* inputs unused
    float* out = (float*)d_out;

    mask1_kernel<<<(Bn * HWn) / 256, 256, 0, stream>>>(world);
    mask2_kernel<<<(Bn * HWn) / 256, 256, 0, stream>>>(world);
    final_kernel<<<(Bn * (Hn / Rn) * CGn * (Wn / 4)) / 256, 256, 0, stream>>>(world, out);
}